// Round 2
// baseline (1102.098 us; speedup 1.0000x reference)
//
#include <hip/hip_runtime.h>
#include <stdint.h>

// B=4, S=2048, D=512, H=8, DK=DV=64
typedef __attribute__((ext_vector_type(8))) short short8;
typedef __attribute__((ext_vector_type(4))) float f32x4;
typedef __attribute__((ext_vector_type(4))) unsigned short ushort4v;

__device__ __forceinline__ unsigned short f2bf(float f) {
    union { float f; uint32_t u; } v; v.f = f;
    return (unsigned short)((v.u + 0x7FFFu + ((v.u >> 16) & 1u)) >> 16);
}
__device__ __forceinline__ float bf2f(unsigned short h) {
    union { uint32_t u; float f; } v; v.u = ((uint32_t)h) << 16;
    return v.f;
}

// ---------------- Kernel 1: tiled transpose W[k][n] f32 -> Wt[n][k] bf16 ----------------
__global__ __launch_bounds__(256) void prep_wt_kernel(
    const float* __restrict__ W0, const float* __restrict__ W1,
    const float* __restrict__ W2, const float* __restrict__ W3,
    unsigned short* __restrict__ Wt)
{
    __shared__ unsigned short tile[64][66];
    const float* W = blockIdx.y == 0 ? W0 : blockIdx.y == 1 ? W1 : blockIdx.y == 2 ? W2 : W3;
    unsigned short* dst = Wt + (size_t)blockIdx.y * (512 * 512);
    const int k0 = (blockIdx.x >> 3) * 64;
    const int n0 = (blockIdx.x & 7) * 64;
    const int nx = threadIdx.x & 63;
    const int ty = threadIdx.x >> 6;
#pragma unroll
    for (int i = 0; i < 16; ++i) {
        const int kl = i * 4 + ty;
        tile[nx][kl] = f2bf(W[(size_t)(k0 + kl) * 512 + n0 + nx]);
    }
    __syncthreads();
#pragma unroll
    for (int i = 0; i < 16; ++i) {
        const int nl = i * 4 + ty;
        dst[(size_t)(n0 + nl) * 512 + k0 + nx] = tile[nl][nx];
    }
}

// ---------------- Kernel 2: Q/K/V projections (hi/lo split A for precision) ----------------
// which=0: Q -> [bh][s][64] bf16 ; which=1: K -> same ; which=2: V -> VT [bh][64][s] bf16
__global__ __launch_bounds__(256) void proj_kernel(
    const float* __restrict__ inQ, const float* __restrict__ inK, const float* __restrict__ inV,
    const unsigned short* __restrict__ Wt,
    unsigned short* __restrict__ outQ, unsigned short* __restrict__ outK,
    unsigned short* __restrict__ outVT)
{
    const int which = blockIdx.y;
    const float* inp = which == 0 ? inQ : which == 1 ? inK : inV;
    const unsigned short* Wtb = Wt + (size_t)which * (512 * 512);
    const int tid = threadIdx.x;
    const int wid = tid >> 6, l = tid & 63;
    const int rt = wid >> 1, ch = wid & 1;
    const int lrow = l & 15, g = l >> 4;
    const int rowbase = blockIdx.x * 32;
    const int arow = rowbase + rt * 16 + lrow;

    f32x4 acc[16];
#pragma unroll
    for (int t = 0; t < 16; ++t) acc[t] = (f32x4){0.f, 0.f, 0.f, 0.f};

    for (int k0 = 0; k0 < 512; k0 += 32) {
        const float* ap = inp + (size_t)arow * 512 + k0 + g * 8;
        float4 a0 = *(const float4*)ap;
        float4 a1 = *(const float4*)(ap + 4);
        float av[8] = {a0.x, a0.y, a0.z, a0.w, a1.x, a1.y, a1.z, a1.w};
        short8 hi, lo;
#pragma unroll
        for (int j = 0; j < 8; ++j) {
            unsigned short hb = f2bf(av[j]);
            hi[j] = (short)hb;
            lo[j] = (short)f2bf(av[j] - bf2f(hb));
        }
#pragma unroll
        for (int t = 0; t < 16; ++t) {
            const int n = ch * 256 + t * 16 + lrow;
            short8 bf = *(const short8*)(Wtb + (size_t)n * 512 + k0 + g * 8);
            acc[t] = __builtin_amdgcn_mfma_f32_16x16x32_bf16(hi, bf, acc[t], 0, 0, 0);
            acc[t] = __builtin_amdgcn_mfma_f32_16x16x32_bf16(lo, bf, acc[t], 0, 0, 0);
        }
    }

    if (which == 2) {
#pragma unroll
        for (int t = 0; t < 16; ++t) {
            const int n = ch * 256 + t * 16 + lrow;
            const int hh = n >> 6, dd = n & 63;
            const int row0 = rowbase + rt * 16 + g * 4;
            const int bb = row0 >> 11, s0 = row0 & 2047;
            ushort4v pk;
            pk[0] = f2bf(acc[t][0]); pk[1] = f2bf(acc[t][1]);
            pk[2] = f2bf(acc[t][2]); pk[3] = f2bf(acc[t][3]);
            *(ushort4v*)(outVT + ((size_t)(bb * 8 + hh) * 64 + dd) * 2048 + s0) = pk;
        }
    } else {
        unsigned short* dst = which == 0 ? outQ : outK;
#pragma unroll
        for (int t = 0; t < 16; ++t) {
            const int n = ch * 256 + t * 16 + lrow;
            const int hh = n >> 6, dd = n & 63;
#pragma unroll
            for (int r = 0; r < 4; ++r) {
                const int row = rowbase + rt * 16 + g * 4 + r;
                const int bb = row >> 11, s0 = row & 2047;
                dst[((size_t)(bb * 8 + hh) * 2048 + s0) * 64 + dd] = f2bf(acc[t][r]);
            }
        }
    }
}

// ---------------- Kernel 3: fused attention ----------------
// 1 WG = (b,h, 16 q-rows), 256 threads (4 waves), LDS 64KB -> 2 WG/CU.
// Phase 1 computes S^T = mfma(K,Q): lane owns q=l&15, k=(l>>4)*4+r -> 4 consecutive k:
// one uchar4 mask load + one ds_write_b64 per 16x16 tile.
// P row byte layout: off = (k*2) ^ ((q&7)<<4)  (XOR swizzle, bank-conflict-free reads).
__global__ __launch_bounds__(256) void attn_kernel(
    const unsigned short* __restrict__ Qw, const unsigned short* __restrict__ Kw,
    const unsigned short* __restrict__ VT, const unsigned char* __restrict__ mask,
    float* __restrict__ attn_out, float* __restrict__ ctx)
{
    extern __shared__ char smem[];
    float* rowsum = (float*)(smem + 16 * 4096);
    // XCD-bijective remap: L&7 selects XCD; each XCD owns bh in {x,8+x,16+x,24+x}.
    const int L = blockIdx.x;
    const int xcd = L & 7, idx = L >> 3;
    const int q7 = idx & 127;
    const int bh = ((idx >> 7) << 3) | xcd;
    const int b = bh >> 3, h = bh & 7;
    const int qg0 = q7 * 16;
    const int tid = threadIdx.x, wid = tid >> 6, l = tid & 63;
    const int lrow = l & 15, g = l >> 4;

    if (tid < 16) rowsum[tid] = 0.f;
    __syncthreads();

    // ---- Phase 1: S^T tiles, mask, exp, rowsum, P -> LDS ----
    {
        const unsigned short* qp = Qw + ((size_t)bh * 2048 + qg0 + lrow) * 64 + g * 8;
        const short8 qf0 = *(const short8*)qp;
        const short8 qf1 = *(const short8*)(qp + 32);
        float psum = 0.f;
        const unsigned char* mrow = mask + ((size_t)b * 2048 + qg0 + lrow) * 2048;
        const int sw = (lrow & 7) << 4;
        char* prow = smem + lrow * 4096;
#pragma unroll 2
        for (int i = 0; i < 32; ++i) {
            const int kbase = (wid + i * 4) * 16;
            const unsigned short* kp = Kw + ((size_t)bh * 2048 + kbase + lrow) * 64 + g * 8;
            short8 kf0 = *(const short8*)kp;
            short8 kf1 = *(const short8*)(kp + 32);
            f32x4 sc = (f32x4){0.f, 0.f, 0.f, 0.f};
            sc = __builtin_amdgcn_mfma_f32_16x16x32_bf16(kf0, qf0, sc, 0, 0, 0);
            sc = __builtin_amdgcn_mfma_f32_16x16x32_bf16(kf1, qf1, sc, 0, 0, 0);
            const uint32_t m4 = *(const uint32_t*)(mrow + kbase + g * 4);
            ushort4v pk;
#pragma unroll
            for (int r = 0; r < 4; ++r) {
                // exp(score/8) = exp2(score * 0.125 * log2(e))
                const float e = ((m4 >> (8 * r)) & 255u) ? 0.f
                                : exp2f(sc[r] * 0.180336880f);
                psum += e;
                pk[r] = f2bf(e);
            }
            *(ushort4v*)(prow + ((kbase * 2 + g * 8) ^ sw)) = pk;
        }
        psum += __shfl_xor(psum, 16);
        psum += __shfl_xor(psum, 32);
        if (l < 16) atomicAdd(&rowsum[l], psum);
    }
    __syncthreads();

    // ---- Phase 2a: PV (all 4 waves, one 16-col V tile each) ----
    {
        const int ct = wid;
        f32x4 acc0 = (f32x4){0.f,0.f,0.f,0.f}, acc1 = (f32x4){0.f,0.f,0.f,0.f};
        const unsigned short* vb = VT + ((size_t)bh * 64 + ct * 16 + lrow) * 2048 + g * 8;
        char* prow = smem + lrow * 4096;
        const int sw = (lrow & 7) << 4;
        for (int ks = 0; ks < 64; ks += 2) {
            short8 pa0 = *(const short8*)(prow + ((ks * 64 + g * 16) ^ sw));
            short8 vb0 = *(const short8*)(vb + ks * 32);
            acc0 = __builtin_amdgcn_mfma_f32_16x16x32_bf16(pa0, vb0, acc0, 0, 0, 0);
            short8 pa1 = *(const short8*)(prow + (((ks + 1) * 64 + g * 16) ^ sw));
            short8 vb1 = *(const short8*)(vb + (ks + 1) * 32);
            acc1 = __builtin_amdgcn_mfma_f32_16x16x32_bf16(pa1, vb1, acc1, 0, 0, 0);
        }
#pragma unroll
        for (int r = 0; r < 4; ++r) {
            const int q = g * 4 + r;
            const float rinv = 1.0f / rowsum[q];
            ctx[((size_t)b * 2048 + qg0 + q) * 512 + h * 64 + ct * 16 + lrow] =
                (acc0[r] + acc1[r]) * rinv;
        }
    }

    // ---- Phase 2b: stream normalized attn rows to HBM (all 4 waves) ----
    {
#pragma unroll
        for (int rr = 0; rr < 4; ++rr) {
            const int row = wid * 4 + rr;
            const float rinv = 1.0f / rowsum[row];
            float* gp = attn_out + ((size_t)bh * 2048 + qg0 + row) * 2048 + 2 * l;
            const char* pr = smem + row * 4096;
            const int swr = (row & 7) << 4;
#pragma unroll 4
            for (int c0 = 0; c0 < 2048; c0 += 128) {
                const uint32_t u = *(const uint32_t*)(pr + (((c0 + 2 * l) * 2) ^ swr));
                float2 o;
                o.x = bf2f((unsigned short)(u & 0xFFFFu)) * rinv;
                o.y = bf2f((unsigned short)(u >> 16)) * rinv;
                *(float2*)(gp + c0) = o;
            }
        }
    }
}

// ---------------- Kernel 4: fc + residual + LayerNorm (ctx f32, hi/lo split A) ----------------
__global__ __launch_bounds__(256) void fc_ln_kernel(
    const float* __restrict__ ctx, const unsigned short* __restrict__ Wtfc,
    const float* __restrict__ resid, const float* __restrict__ gamma,
    const float* __restrict__ beta, float* __restrict__ out)
{
    __shared__ float red[32][2][2];
    const int tid = threadIdx.x;
    const int wid = tid >> 6, l = tid & 63;
    const int rt = wid >> 1, ch = wid & 1;
    const int lrow = l & 15, g = l >> 4;
    const int rowbase = blockIdx.x * 32;
    const int arow = rowbase + rt * 16 + lrow;

    f32x4 acc[16];
#pragma unroll
    for (int t = 0; t < 16; ++t) acc[t] = (f32x4){0.f, 0.f, 0.f, 0.f};

    for (int k0 = 0; k0 < 512; k0 += 32) {
        const float* ap = ctx + (size_t)arow * 512 + k0 + g * 8;
        float4 a0 = *(const float4*)ap;
        float4 a1 = *(const float4*)(ap + 4);
        float av[8] = {a0.x, a0.y, a0.z, a0.w, a1.x, a1.y, a1.z, a1.w};
        short8 hi, lo;
#pragma unroll
        for (int j = 0; j < 8; ++j) {
            unsigned short hb = f2bf(av[j]);
            hi[j] = (short)hb;
            lo[j] = (short)f2bf(av[j] - bf2f(hb));
        }
#pragma unroll
        for (int t = 0; t < 16; ++t) {
            const int n = ch * 256 + t * 16 + lrow;
            short8 bf = *(const short8*)(Wtfc + (size_t)n * 512 + k0 + g * 8);
            acc[t] = __builtin_amdgcn_mfma_f32_16x16x32_bf16(hi, bf, acc[t], 0, 0, 0);
            acc[t] = __builtin_amdgcn_mfma_f32_16x16x32_bf16(lo, bf, acc[t], 0, 0, 0);
        }
    }

    float s1[4] = {0,0,0,0}, s2[4] = {0,0,0,0};
#pragma unroll
    for (int t = 0; t < 16; ++t) {
        const int n = ch * 256 + t * 16 + lrow;
#pragma unroll
        for (int r = 0; r < 4; ++r) {
            const int row = rowbase + rt * 16 + g * 4 + r;
            float v = acc[t][r] + resid[(size_t)row * 512 + n];
            acc[t][r] = v;
            s1[r] += v;
            s2[r] += v * v;
        }
    }
#pragma unroll
    for (int r = 0; r < 4; ++r) {
        s1[r] += __shfl_xor(s1[r], 1); s2[r] += __shfl_xor(s2[r], 1);
        s1[r] += __shfl_xor(s1[r], 2); s2[r] += __shfl_xor(s2[r], 2);
        s1[r] += __shfl_xor(s1[r], 4); s2[r] += __shfl_xor(s2[r], 4);
        s1[r] += __shfl_xor(s1[r], 8); s2[r] += __shfl_xor(s2[r], 8);
    }
    if (lrow == 0) {
#pragma unroll
        for (int r = 0; r < 4; ++r) {
            red[rt * 16 + g * 4 + r][ch][0] = s1[r];
            red[rt * 16 + g * 4 + r][ch][1] = s2[r];
        }
    }
    __syncthreads();
    float mean[4], rstd[4];
#pragma unroll
    for (int r = 0; r < 4; ++r) {
        const int rl = rt * 16 + g * 4 + r;
        const float S1 = red[rl][0][0] + red[rl][1][0];
        const float S2 = red[rl][0][1] + red[rl][1][1];
        mean[r] = S1 * (1.0f / 512.0f);
        const float var = S2 * (1.0f / 512.0f) - mean[r] * mean[r];
        rstd[r] = rsqrtf(var + 1e-5f);
    }
#pragma unroll
    for (int t = 0; t < 16; ++t) {
        const int n = ch * 256 + t * 16 + lrow;
        const float gm = gamma[n], bt = beta[n];
#pragma unroll
        for (int r = 0; r < 4; ++r) {
            const int row = rowbase + rt * 16 + g * 4 + r;
            out[(size_t)row * 512 + n] = (acc[t][r] - mean[r]) * rstd[r] * gm + bt;
        }
    }
}

// ---------------- Host launcher ----------------
extern "C" void kernel_launch(void* const* d_in, const int* in_sizes, int n_in,
                              void* d_out, int out_size, void* d_ws, size_t ws_size,
                              hipStream_t stream)
{
    (void)in_sizes; (void)n_in; (void)out_size; (void)ws_size;
    const float* inQ = (const float*)d_in[0];
    const float* inK = (const float*)d_in[1];
    const float* inV = (const float*)d_in[2];
    const unsigned char* mask = (const unsigned char*)d_in[3];  // np.bool_ -> 1 byte
    const float* WQ  = (const float*)d_in[4];
    const float* WK  = (const float*)d_in[5];
    const float* WV  = (const float*)d_in[6];
    const float* Wfc = (const float*)d_in[7];
    const float* gamma = (const float*)d_in[8];
    const float* beta  = (const float*)d_in[9];

    char* ws = (char*)d_ws;
    unsigned short* wsQ   = (unsigned short*)(ws);                           // 8 MB
    unsigned short* wsK   = (unsigned short*)(ws + ((size_t)8  << 20));      // 8 MB
    unsigned short* wsVT  = (unsigned short*)(ws + ((size_t)16 << 20));      // 8 MB
    float*          wsCtx = (float*)         (ws + ((size_t)24 << 20));      // 16 MB (f32)
    unsigned short* wsWt  = (unsigned short*)(ws + ((size_t)40 << 20));      // 2 MB

    float* out_ln   = (float*)d_out;
    float* out_attn = out_ln + (size_t)4 * 2048 * 512;

    prep_wt_kernel<<<dim3(64, 4), dim3(256), 0, stream>>>(WQ, WK, WV, Wfc, wsWt);
    proj_kernel<<<dim3(256, 3), dim3(256), 0, stream>>>(inQ, inK, inV, wsWt, wsQ, wsK, wsVT);

    const int smem_bytes = 16 * 4096 + 64;
    hipFuncSetAttribute((const void*)attn_kernel,
                        hipFuncAttributeMaxDynamicSharedMemorySize, smem_bytes);
    attn_kernel<<<dim3(4096), dim3(256), smem_bytes, stream>>>(wsQ, wsK, wsVT, mask,
                                                               out_attn, wsCtx);
    fc_ln_kernel<<<dim3(256), dim3(256), 0, stream>>>(wsCtx, wsWt + (size_t)3 * 512 * 512,
                                                      inQ, gamma, beta, out_ln);
}

// Round 4
// 1002.321 us; speedup vs baseline: 1.0995x; 1.0995x over previous
//
#include <hip/hip_runtime.h>
#include <stdint.h>

// B=4, S=2048, D=512, H=8, DK=DV=64
typedef __attribute__((ext_vector_type(8))) short short8;
typedef __attribute__((ext_vector_type(4))) float f32x4;
typedef __attribute__((ext_vector_type(16))) float f32x16;
typedef __attribute__((ext_vector_type(4))) unsigned short ushort4v;
typedef __attribute__((ext_vector_type(4))) int int4v;

__device__ __forceinline__ unsigned short f2bf(float f) {
    union { float f; uint32_t u; } v; v.f = f;
    return (unsigned short)((v.u + 0x7FFFu + ((v.u >> 16) & 1u)) >> 16);
}
__device__ __forceinline__ float bf2f(unsigned short h) {
    union { uint32_t u; float f; } v; v.u = ((uint32_t)h) << 16;
    return v.f;
}

// ---------------- Kernel 1: tiled transpose W[k][n] f32 -> Wt[n][k] bf16 ----------------
__global__ __launch_bounds__(256) void prep_wt_kernel(
    const float* __restrict__ W0, const float* __restrict__ W1,
    const float* __restrict__ W2, const float* __restrict__ W3,
    unsigned short* __restrict__ Wt)
{
    __shared__ unsigned short tile[64][66];
    const float* W = blockIdx.y == 0 ? W0 : blockIdx.y == 1 ? W1 : blockIdx.y == 2 ? W2 : W3;
    unsigned short* dst = Wt + (size_t)blockIdx.y * (512 * 512);
    const int k0 = (blockIdx.x >> 3) * 64;
    const int n0 = (blockIdx.x & 7) * 64;
    const int nx = threadIdx.x & 63;
    const int ty = threadIdx.x >> 6;
#pragma unroll
    for (int i = 0; i < 16; ++i) {
        const int kl = i * 4 + ty;
        tile[nx][kl] = f2bf(W[(size_t)(k0 + kl) * 512 + n0 + nx]);
    }
    __syncthreads();
#pragma unroll
    for (int i = 0; i < 16; ++i) {
        const int nl = i * 4 + ty;
        dst[(size_t)(n0 + nl) * 512 + k0 + nx] = tile[nl][nx];
    }
}

// ---------------- Kernel 2: Q/K/V projections ----------------
// which=0: Q -> [bh][s][64] bf16 ; which=1: K -> same ; which=2: V -> VT [bh][64][s] bf16
__global__ __launch_bounds__(256) void proj_kernel(
    const float* __restrict__ inQ, const float* __restrict__ inK, const float* __restrict__ inV,
    const unsigned short* __restrict__ Wt,
    unsigned short* __restrict__ outQ, unsigned short* __restrict__ outK,
    unsigned short* __restrict__ outVT)
{
    const int which = blockIdx.y;
    const float* inp = which == 0 ? inQ : which == 1 ? inK : inV;
    const unsigned short* Wtb = Wt + (size_t)which * (512 * 512);
    const int tid = threadIdx.x;
    const int wid = tid >> 6, l = tid & 63;
    const int rt = wid >> 1, ch = wid & 1;
    const int lrow = l & 15, g = l >> 4;
    const int rowbase = blockIdx.x * 32;
    const int arow = rowbase + rt * 16 + lrow;

    f32x4 acc[16];
#pragma unroll
    for (int t = 0; t < 16; ++t) acc[t] = (f32x4){0.f, 0.f, 0.f, 0.f};

    for (int k0 = 0; k0 < 512; k0 += 32) {
        const float* ap = inp + (size_t)arow * 512 + k0 + g * 8;
        float4 a0 = *(const float4*)ap;
        float4 a1 = *(const float4*)(ap + 4);
        short8 af;
        af[0] = (short)f2bf(a0.x); af[1] = (short)f2bf(a0.y);
        af[2] = (short)f2bf(a0.z); af[3] = (short)f2bf(a0.w);
        af[4] = (short)f2bf(a1.x); af[5] = (short)f2bf(a1.y);
        af[6] = (short)f2bf(a1.z); af[7] = (short)f2bf(a1.w);
#pragma unroll
        for (int t = 0; t < 16; ++t) {
            const int n = ch * 256 + t * 16 + lrow;
            short8 bf = *(const short8*)(Wtb + (size_t)n * 512 + k0 + g * 8);
            acc[t] = __builtin_amdgcn_mfma_f32_16x16x32_bf16(af, bf, acc[t], 0, 0, 0);
        }
    }

    if (which == 2) {
#pragma unroll
        for (int t = 0; t < 16; ++t) {
            const int n = ch * 256 + t * 16 + lrow;
            const int hh = n >> 6, dd = n & 63;
            const int row0 = rowbase + rt * 16 + g * 4;
            const int bb = row0 >> 11, s0 = row0 & 2047;
            ushort4v pk;
            pk[0] = f2bf(acc[t][0]); pk[1] = f2bf(acc[t][1]);
            pk[2] = f2bf(acc[t][2]); pk[3] = f2bf(acc[t][3]);
            *(ushort4v*)(outVT + ((size_t)(bb * 8 + hh) * 64 + dd) * 2048 + s0) = pk;
        }
    } else {
        unsigned short* dst = which == 0 ? outQ : outK;
#pragma unroll
        for (int t = 0; t < 16; ++t) {
            const int n = ch * 256 + t * 16 + lrow;
            const int hh = n >> 6, dd = n & 63;
#pragma unroll
            for (int r = 0; r < 4; ++r) {
                const int row = rowbase + rt * 16 + g * 4 + r;
                const int bb = row >> 11, s0 = row & 2047;
                dst[((size_t)(bb * 8 + hh) * 2048 + s0) * 64 + dd] = f2bf(acc[t][r]);
            }
        }
    }
}

// ---------------- Kernel 3: fused attention, two-pass recompute, no P buffer ----------------
// WG = 4 waves = one 32-q block of one (b,h). Wave w owns k in [w*512,(w+1)*512).
// S^T tile via mfma_32x32x16(K,Q): col=q=lane&31, row k=(r&3)+8*(r>>2)+4*(lane>>5).
// Pass A: rowsum of exp. Pass B: recompute, write normalized attn f32 from regs,
// pack e->bf16 + v_permlane32_swap_b32 -> PV B-frag directly, accumulate ctx.
__global__ __launch_bounds__(256, 4) void attn_kernel(
    const unsigned short* __restrict__ Qw, const unsigned short* __restrict__ Kw,
    const unsigned short* __restrict__ VT, const unsigned char* __restrict__ mask,
    float* __restrict__ attn_out, float* __restrict__ ctx)
{
    __shared__ float psum_lds[4][32];
    __shared__ float ctx_lds[4][32][67];   // pad 67: bank = (3q+d)%32, conflict-free

    // XCD swizzle: xcd = L&7 (dispatch round-robin); each XCD owns 4 consecutive bh.
    const int L = blockIdx.x;
    const int xcd = L & 7, j = L >> 3;
    const int bh = xcd * 4 + (j >> 6);
    const int qb = j & 63;
    const int b = bh >> 3, h = bh & 7;
    const int qg0 = qb * 32;
    const int tid = threadIdx.x, wid = tid >> 6, l = tid & 63;
    const int lq = l & 31, hi = l >> 5;
    const float EXPC = 0.18033688011112042f;   // (1/8)*log2(e)

    // Q B-fragments (persistent): B[d][q], lane: d = d0 + 8*hi + jj, q = lq
    const unsigned short* qbase = Qw + ((size_t)bh * 2048 + qg0 + lq) * 64 + 8 * hi;
    short8 qf[4];
#pragma unroll
    for (int d4 = 0; d4 < 4; ++d4) qf[d4] = *(const short8*)(qbase + d4 * 16);

    const int k0w = wid * 512;
    const unsigned char* mbase = mask + ((size_t)b * 2048 + qg0 + lq) * 2048 + 4 * hi;
    const unsigned short* kwb = Kw + ((size_t)bh * 2048 + lq) * 64 + 8 * hi;

    // ---- Pass A: rowsum ----
    float psum = 0.f;
    for (int t = 0; t < 16; ++t) {
        const int kb = k0w + t * 32;
        const unsigned short* kp = kwb + (size_t)kb * 64;
        short8 kf0 = *(const short8*)(kp);
        short8 kf1 = *(const short8*)(kp + 16);
        short8 kf2 = *(const short8*)(kp + 32);
        short8 kf3 = *(const short8*)(kp + 48);
        f32x16 sc = (f32x16)(0.f);
        sc = __builtin_amdgcn_mfma_f32_32x32x16_bf16(kf0, qf[0], sc, 0, 0, 0);
        sc = __builtin_amdgcn_mfma_f32_32x32x16_bf16(kf1, qf[1], sc, 0, 0, 0);
        sc = __builtin_amdgcn_mfma_f32_32x32x16_bf16(kf2, qf[2], sc, 0, 0, 0);
        sc = __builtin_amdgcn_mfma_f32_32x32x16_bf16(kf3, qf[3], sc, 0, 0, 0);
#pragma unroll
        for (int c2 = 0; c2 < 4; ++c2) {
            const uint32_t m4 = *(const uint32_t*)(mbase + kb + 8 * c2);
#pragma unroll
            for (int rr = 0; rr < 4; ++rr) {
                const float e = ((m4 >> (8 * rr)) & 255u) ? 0.f
                                : exp2f(sc[c2 * 4 + rr] * EXPC);
                psum += e;
            }
        }
    }
    psum += __shfl_xor(psum, 32);          // combine hi/lo k-halves (same q)
    if (l < 32) psum_lds[wid][l] = psum;
    __syncthreads();
    const float rinv = 1.0f / (psum_lds[0][lq] + psum_lds[1][lq] +
                               psum_lds[2][lq] + psum_lds[3][lq]);

    // ---- Pass B: recompute, write attn, PV accumulate ----
    f32x16 acc0 = (f32x16)(0.f), acc1 = (f32x16)(0.f);
    float* abase = attn_out + ((size_t)bh * 2048 + qg0 + lq) * 2048 + 4 * hi;
    const unsigned short* vb0 = VT + ((size_t)bh * 64 + lq) * 2048 + 8 * hi;
    const unsigned short* vb1 = vb0 + (size_t)32 * 2048;

    for (int t = 0; t < 16; ++t) {
        const int kb = k0w + t * 32;
        const unsigned short* kp = kwb + (size_t)kb * 64;
        short8 kf0 = *(const short8*)(kp);
        short8 kf1 = *(const short8*)(kp + 16);
        short8 kf2 = *(const short8*)(kp + 32);
        short8 kf3 = *(const short8*)(kp + 48);
        f32x16 sc = (f32x16)(0.f);
        sc = __builtin_amdgcn_mfma_f32_32x32x16_bf16(kf0, qf[0], sc, 0, 0, 0);
        sc = __builtin_amdgcn_mfma_f32_32x32x16_bf16(kf1, qf[1], sc, 0, 0, 0);
        sc = __builtin_amdgcn_mfma_f32_32x32x16_bf16(kf2, qf[2], sc, 0, 0, 0);
        sc = __builtin_amdgcn_mfma_f32_32x32x16_bf16(kf3, qf[3], sc, 0, 0, 0);

        float e[16];
#pragma unroll
        for (int c2 = 0; c2 < 4; ++c2) {
            const uint32_t m4 = *(const uint32_t*)(mbase + kb + 8 * c2);
#pragma unroll
            for (int rr = 0; rr < 4; ++rr) {
                e[c2 * 4 + rr] = ((m4 >> (8 * rr)) & 255u) ? 0.f
                                 : exp2f(sc[c2 * 4 + rr] * EXPC) * rinv;
            }
        }
        // write normalized attn rows straight from registers (f32)
#pragma unroll
        for (int c2 = 0; c2 < 4; ++c2) {
            float4 st = {e[c2 * 4 + 0], e[c2 * 4 + 1], e[c2 * 4 + 2], e[c2 * 4 + 3]};
            *(float4*)(abase + kb + 8 * c2) = st;
        }
        // pack -> bf16, permlane swap -> PV B-fragments, 2 k-halves of 16
#pragma unroll
        for (int kh = 0; kh < 2; ++kh) {
            const int cA = 2 * kh, cB = 2 * kh + 1;
            uint32_t w0 = (uint32_t)f2bf(e[4 * cA + 0]) | ((uint32_t)f2bf(e[4 * cA + 1]) << 16);
            uint32_t w1 = (uint32_t)f2bf(e[4 * cB + 0]) | ((uint32_t)f2bf(e[4 * cB + 1]) << 16);
            uint32_t w2 = (uint32_t)f2bf(e[4 * cA + 2]) | ((uint32_t)f2bf(e[4 * cA + 3]) << 16);
            uint32_t w3 = (uint32_t)f2bf(e[4 * cB + 2]) | ((uint32_t)f2bf(e[4 * cB + 3]) << 16);
            // dst.hi <-> src.lo : new w0 = k+8*hi+{0,1}, new w1 = k+4+8*hi+{0,1}
            asm("v_permlane32_swap_b32 %0, %1" : "+v"(w0), "+v"(w1));
            asm("v_permlane32_swap_b32 %0, %1" : "+v"(w2), "+v"(w3));
            int4v pw = {(int)w0, (int)w2, (int)w1, (int)w3};
            short8 pb = *(short8*)&pw;
            const size_t voff = (size_t)(kb + 16 * kh);
            short8 v0 = *(const short8*)(vb0 + voff);
            short8 v1 = *(const short8*)(vb1 + voff);
            acc0 = __builtin_amdgcn_mfma_f32_32x32x16_bf16(v0, pb, acc0, 0, 0, 0);
            acc1 = __builtin_amdgcn_mfma_f32_32x32x16_bf16(v1, pb, acc1, 0, 0, 0);
        }
    }

    // partial ctx -> LDS
#pragma unroll
    for (int r = 0; r < 16; ++r) {
        const int d = (r & 3) + 8 * (r >> 2) + 4 * hi;
        ctx_lds[wid][lq][d] = acc0[r];
        ctx_lds[wid][lq][d + 32] = acc1[r];
    }
    __syncthreads();
    // reduce 4 partials, write ctx f32 (each wave covers one q-row of 64 per iter)
#pragma unroll
    for (int i = 0; i < 8; ++i) {
        const int idx = i * 256 + tid;
        const int q = idx >> 6, d = idx & 63;
        const float s = ctx_lds[0][q][d] + ctx_lds[1][q][d] +
                        ctx_lds[2][q][d] + ctx_lds[3][q][d];
        ctx[((size_t)b * 2048 + qg0 + q) * 512 + h * 64 + d] = s;
    }
}

// ---------------- Kernel 4: fc + residual + LayerNorm (ctx f32) ----------------
__global__ __launch_bounds__(256) void fc_ln_kernel(
    const float* __restrict__ ctx, const unsigned short* __restrict__ Wtfc,
    const float* __restrict__ resid, const float* __restrict__ gamma,
    const float* __restrict__ beta, float* __restrict__ out)
{
    __shared__ float red[32][2][2];
    const int tid = threadIdx.x;
    const int wid = tid >> 6, l = tid & 63;
    const int rt = wid >> 1, ch = wid & 1;
    const int lrow = l & 15, g = l >> 4;
    const int rowbase = blockIdx.x * 32;
    const int arow = rowbase + rt * 16 + lrow;

    f32x4 acc[16];
#pragma unroll
    for (int t = 0; t < 16; ++t) acc[t] = (f32x4){0.f, 0.f, 0.f, 0.f};

    for (int k0 = 0; k0 < 512; k0 += 32) {
        const float* ap = ctx + (size_t)arow * 512 + k0 + g * 8;
        float4 a0 = *(const float4*)ap;
        float4 a1 = *(const float4*)(ap + 4);
        short8 af;
        af[0] = (short)f2bf(a0.x); af[1] = (short)f2bf(a0.y);
        af[2] = (short)f2bf(a0.z); af[3] = (short)f2bf(a0.w);
        af[4] = (short)f2bf(a1.x); af[5] = (short)f2bf(a1.y);
        af[6] = (short)f2bf(a1.z); af[7] = (short)f2bf(a1.w);
#pragma unroll
        for (int t = 0; t < 16; ++t) {
            const int n = ch * 256 + t * 16 + lrow;
            short8 bf = *(const short8*)(Wtfc + (size_t)n * 512 + k0 + g * 8);
            acc[t] = __builtin_amdgcn_mfma_f32_16x16x32_bf16(af, bf, acc[t], 0, 0, 0);
        }
    }

    float s1[4] = {0,0,0,0}, s2[4] = {0,0,0,0};
#pragma unroll
    for (int t = 0; t < 16; ++t) {
        const int n = ch * 256 + t * 16 + lrow;
#pragma unroll
        for (int r = 0; r < 4; ++r) {
            const int row = rowbase + rt * 16 + g * 4 + r;
            float v = acc[t][r] + resid[(size_t)row * 512 + n];
            acc[t][r] = v;
            s1[r] += v;
            s2[r] += v * v;
        }
    }
#pragma unroll
    for (int r = 0; r < 4; ++r) {
        s1[r] += __shfl_xor(s1[r], 1); s2[r] += __shfl_xor(s2[r], 1);
        s1[r] += __shfl_xor(s1[r], 2); s2[r] += __shfl_xor(s2[r], 2);
        s1[r] += __shfl_xor(s1[r], 4); s2[r] += __shfl_xor(s2[r], 4);
        s1[r] += __shfl_xor(s1[r], 8); s2[r] += __shfl_xor(s2[r], 8);
    }
    if (lrow == 0) {
#pragma unroll
        for (int r = 0; r < 4; ++r) {
            red[rt * 16 + g * 4 + r][ch][0] = s1[r];
            red[rt * 16 + g * 4 + r][ch][1] = s2[r];
        }
    }
    __syncthreads();
    float mean[4], rstd[4];
#pragma unroll
    for (int r = 0; r < 4; ++r) {
        const int rl = rt * 16 + g * 4 + r;
        const float S1 = red[rl][0][0] + red[rl][1][0];
        const float S2 = red[rl][0][1] + red[rl][1][1];
        mean[r] = S1 * (1.0f / 512.0f);
        const float var = S2 * (1.0f / 512.0f) - mean[r] * mean[r];
        rstd[r] = rsqrtf(var + 1e-5f);
    }
#pragma unroll
    for (int t = 0; t < 16; ++t) {
        const int n = ch * 256 + t * 16 + lrow;
        const float gm = gamma[n], bt = beta[n];
#pragma unroll
        for (int r = 0; r < 4; ++r) {
            const int row = rowbase + rt * 16 + g * 4 + r;
            out[(size_t)row * 512 + n] = (acc[t][r] - mean[r]) * rstd[r] * gm + bt;
        }
    }
}

// ---------------- Host launcher ----------------
extern "C" void kernel_launch(void* const* d_in, const int* in_sizes, int n_in,
                              void* d_out, int out_size, void* d_ws, size_t ws_size,
                              hipStream_t stream)
{
    (void)in_sizes; (void)n_in; (void)out_size; (void)ws_size;
    const float* inQ = (const float*)d_in[0];
    const float* inK = (const float*)d_in[1];
    const float* inV = (const float*)d_in[2];
    const unsigned char* mask = (const unsigned char*)d_in[3];  // np.bool_ -> 1 byte
    const float* WQ  = (const float*)d_in[4];
    const float* WK  = (const float*)d_in[5];
    const float* WV  = (const float*)d_in[6];
    const float* Wfc = (const float*)d_in[7];
    const float* gamma = (const float*)d_in[8];
    const float* beta  = (const float*)d_in[9];

    char* ws = (char*)d_ws;
    unsigned short* wsQ   = (unsigned short*)(ws);                           // 8 MB
    unsigned short* wsK   = (unsigned short*)(ws + ((size_t)8  << 20));      // 8 MB
    unsigned short* wsVT  = (unsigned short*)(ws + ((size_t)16 << 20));      // 8 MB
    float*          wsCtx = (float*)         (ws + ((size_t)24 << 20));      // 16 MB (f32)
    unsigned short* wsWt  = (unsigned short*)(ws + ((size_t)40 << 20));      // 2 MB

    float* out_ln   = (float*)d_out;
    float* out_attn = out_ln + (size_t)4 * 2048 * 512;

    prep_wt_kernel<<<dim3(64, 4), dim3(256), 0, stream>>>(WQ, WK, WV, Wfc, wsWt);
    proj_kernel<<<dim3(256, 3), dim3(256), 0, stream>>>(inQ, inK, inV, wsWt, wsQ, wsK, wsVT);
    attn_kernel<<<dim3(2048), dim3(256), 0, stream>>>(wsQ, wsK, wsVT, mask,
                                                      out_attn, wsCtx);
    fc_ln_kernel<<<dim3(256), dim3(256), 0, stream>>>(wsCtx, wsWt + (size_t)3 * 512 * 512,
                                                      inQ, gamma, beta, out_ln);
}